// Round 6
// baseline (215.148 us; speedup 1.0000x reference)
//
#include <hip/hip_runtime.h>
#include <hip/hip_bf16.h>

// SparseToDense: scatter features [N,32] into dense [B=4, C=32, D=64, H=64, W=64].
// flat_idx (int32 on device) indexes B*D*H*W sites; output is NCDHW. DHW = 2^18.
//
// Strategy (R4): invert the scatter via per-site chains -> no float atomics,
// output written coalesced exactly once, no zero-fill pass.
// R5/R6 refinements:
//   - nontemporal stores (out) + nontemporal loads (feats rows): the 134 MB
//     store stream was thrashing L2 and evicting head/next chain lines.
//     (R6: use clang ext_vector_type for the loads -- __builtin_nontemporal_load
//      rejects HIP_vector_type<float,4>*.)
//   - 2 threads per site (16 ch each): ~half the accumulator VGPRs -> higher
//     occupancy; 2x TLP for chain-walk latency hiding. Lane pairs share the
//     chain (broadcast head/next loads) and split the 128 B feature row into
//     two 64 B halves -> naturally coalesced.

#define DHW_LOG2 18
#define DHW (1 << DHW_LOG2)
#define C_CH 32
#define N_SITES_TOTAL (4 * DHW)   // B=4

typedef float floatx4 __attribute__((ext_vector_type(4)));

__global__ __launch_bounds__(256) void init_head_kernel(int* __restrict__ head, int n)
{
    int t = blockIdx.x * blockDim.x + threadIdx.x;
    if (t < n) head[t] = -1;
}

__global__ __launch_bounds__(256) void build_chains_kernel(
    const int* __restrict__ flat_idx,
    int* __restrict__ head,
    int* __restrict__ next,
    int n_active)
{
    int i = blockIdx.x * blockDim.x + threadIdx.x;
    if (i >= n_active) return;
    int s = flat_idx[i];
    int prev = atomicExch(&head[s], i);   // device-scope int atomic, 4 MB array
    next[i] = prev;
}

__global__ __launch_bounds__(256) void gather_kernel(
    const float* __restrict__ feats,
    const int* __restrict__ head,
    const int* __restrict__ next,
    float* __restrict__ out)
{
    int t = blockIdx.x * blockDim.x + threadIdx.x;
    int S = t >> 1;        // site (lane pairs share a site)
    int h = t & 1;         // channel half: channels h*16 .. h*16+15

    int b  = S >> DHW_LOG2;
    int sp = S & (DHW - 1);

    floatx4 a0 = (floatx4)0.f, a1 = (floatx4)0.f, a2 = (floatx4)0.f, a3 = (floatx4)0.f;

    int p = head[S];       // pair lanes broadcast; cached (L2-resident 4 MB)
    while (p != -1) {
        const floatx4* row = (const floatx4*)(feats + ((size_t)p * C_CH + h * 16));
        int pn = next[p];                        // issue next-hop early (cached)
        floatx4 f0 = __builtin_nontemporal_load(row + 0);   // rows read exactly once
        floatx4 f1 = __builtin_nontemporal_load(row + 1);
        floatx4 f2 = __builtin_nontemporal_load(row + 2);
        floatx4 f3 = __builtin_nontemporal_load(row + 3);
        a0 += f0; a1 += f1; a2 += f2; a3 += f3;
        p = pn;
    }

    // out[(b*32 + c) << 18 | sp], c = h*16 + j. Within a wave each store instr
    // covers two 128 B contiguous segments (one per channel-half group).
    float* o = out + (((size_t)(b * C_CH + h * 16)) << DHW_LOG2) + sp;
    float acc[16] = {
        a0.x, a0.y, a0.z, a0.w,  a1.x, a1.y, a1.z, a1.w,
        a2.x, a2.y, a2.z, a2.w,  a3.x, a3.y, a3.z, a3.w };
    #pragma unroll
    for (int j = 0; j < 16; ++j)
        __builtin_nontemporal_store(acc[j], o + ((size_t)j << DHW_LOG2));
}

// ---- fallback (R3 behavior) if workspace is too small ----
__global__ __launch_bounds__(256) void zero_kernel(float4* __restrict__ out, int n4)
{
    int t = blockIdx.x * blockDim.x + threadIdx.x;
    if (t < n4) out[t] = make_float4(0.f, 0.f, 0.f, 0.f);
}

__global__ __launch_bounds__(256) void scatter_atomic_kernel(
    const float* __restrict__ feats,
    const int* __restrict__ flat_idx,
    float* __restrict__ out,
    int n_active)
{
    int t = blockIdx.x * blockDim.x + threadIdx.x;
    int i = t >> 5, c = t & 31;
    if (i >= n_active) return;
    int s = flat_idx[i];
    atomicAdd(&out[(((size_t)(s >> DHW_LOG2) * C_CH + c) << DHW_LOG2) + (s & (DHW - 1))],
              feats[(size_t)i * C_CH + c]);
}

extern "C" void kernel_launch(void* const* d_in, const int* in_sizes, int n_in,
                              void* d_out, int out_size, void* d_ws, size_t ws_size,
                              hipStream_t stream) {
    const float* feats = (const float*)d_in[0];
    const int*   idx   = (const int*)d_in[1];
    float*       out   = (float*)d_out;
    int n_active = in_sizes[1];   // 400000

    size_t head_bytes = (size_t)N_SITES_TOTAL * sizeof(int);      // 4 MB
    size_t next_bytes = (size_t)n_active * sizeof(int);           // 1.6 MB

    if (ws_size >= head_bytes + next_bytes) {
        int* head = (int*)d_ws;
        int* next = (int*)((char*)d_ws + head_bytes);

        init_head_kernel<<<(N_SITES_TOTAL + 255) / 256, 256, 0, stream>>>(head, N_SITES_TOTAL);
        build_chains_kernel<<<(n_active + 255) / 256, 256, 0, stream>>>(idx, head, next, n_active);
        // 2 threads per site; 2*2^20 threads = 8192 blocks exactly.
        gather_kernel<<<(2 * N_SITES_TOTAL) / 256, 256, 0, stream>>>(feats, head, next, out);
    } else {
        // fallback: R3 atomic path
        int n4 = out_size >> 2;
        zero_kernel<<<(n4 + 255) / 256, 256, 0, stream>>>((float4*)out, n4);
        int total = n_active * C_CH;
        scatter_atomic_kernel<<<(total + 255) / 256, 256, 0, stream>>>(feats, idx, out, n_active);
    }
}

// Round 7
// 203.758 us; speedup vs baseline: 1.0559x; 1.0559x over previous
//
#include <hip/hip_runtime.h>
#include <hip/hip_bf16.h>

// SparseToDense: scatter features [N,32] into dense [B=4, C=32, D=64, H=64, W=64].
// flat_idx (int32 on device) indexes B*D*H*W sites; output is NCDHW. DHW = 2^18.
//
// Strategy (R4): invert the scatter via per-site chains -> no float atomics,
// output written coalesced exactly once, no zero-fill pass.
// R6 post-mortem: nontemporal LOADS of feats rows regressed ~10us — 4x16B
//   no-allocate requests per 64B half-row instead of 1 miss + 3 L1 hits.
//   R7: regular (cached) loads for feats/head/next; KEEP nontemporal stores
//   (the 134 MB output stream must not evict chain data from L2) and KEEP
//   the 2-threads-per-site split (half the accumulator VGPRs, 2x TLP;
//   pair lanes share the chain walk and split the 128 B row into 64 B halves).
// Budget (measured): init ~2us, build ~19us (400k device atomics at ~21/ns
//   fabric rate), gather ~55-68us vs ~34us byte floor.

#define DHW_LOG2 18
#define DHW (1 << DHW_LOG2)
#define C_CH 32
#define N_SITES_TOTAL (4 * DHW)   // B=4

typedef float floatx4 __attribute__((ext_vector_type(4)));

__global__ __launch_bounds__(256) void init_head_kernel(int* __restrict__ head, int n)
{
    int t = blockIdx.x * blockDim.x + threadIdx.x;
    if (t < n) head[t] = -1;
}

__global__ __launch_bounds__(256) void build_chains_kernel(
    const int* __restrict__ flat_idx,
    int* __restrict__ head,
    int* __restrict__ next,
    int n_active)
{
    int i = blockIdx.x * blockDim.x + threadIdx.x;
    if (i >= n_active) return;
    int s = flat_idx[i];
    int prev = atomicExch(&head[s], i);   // device-scope int atomic, 4 MB array
    next[i] = prev;
}

__global__ __launch_bounds__(256) void gather_kernel(
    const float* __restrict__ feats,
    const int* __restrict__ head,
    const int* __restrict__ next,
    float* __restrict__ out)
{
    int t = blockIdx.x * blockDim.x + threadIdx.x;
    int S = t >> 1;        // site (lane pairs share a site)
    int h = t & 1;         // channel half: channels h*16 .. h*16+15

    int b  = S >> DHW_LOG2;
    int sp = S & (DHW - 1);

    floatx4 a0 = (floatx4)0.f, a1 = (floatx4)0.f, a2 = (floatx4)0.f, a3 = (floatx4)0.f;

    int p = head[S];       // pair lanes broadcast; L2-resident 4 MB
    while (p != -1) {
        const floatx4* row = (const floatx4*)(feats + ((size_t)p * C_CH + h * 16));
        int pn = next[p];                 // issue next-hop early
        floatx4 f0 = row[0];              // cached: 1 line fill + 3 L1 hits per 64 B half
        floatx4 f1 = row[1];
        floatx4 f2 = row[2];
        floatx4 f3 = row[3];
        a0 += f0; a1 += f1; a2 += f2; a3 += f3;
        p = pn;
    }

    // out[(b*32 + c) << 18 | sp], c = h*16 + j. Within a wave each store instr
    // covers two 128 B contiguous segments (one per channel-half group).
    float* o = out + (((size_t)(b * C_CH + h * 16)) << DHW_LOG2) + sp;
    float acc[16] = {
        a0.x, a0.y, a0.z, a0.w,  a1.x, a1.y, a1.z, a1.w,
        a2.x, a2.y, a2.z, a2.w,  a3.x, a3.y, a3.z, a3.w };
    #pragma unroll
    for (int j = 0; j < 16; ++j)
        __builtin_nontemporal_store(acc[j], o + ((size_t)j << DHW_LOG2));
}

// ---- fallback (R3 behavior) if workspace is too small ----
__global__ __launch_bounds__(256) void zero_kernel(float4* __restrict__ out, int n4)
{
    int t = blockIdx.x * blockDim.x + threadIdx.x;
    if (t < n4) out[t] = make_float4(0.f, 0.f, 0.f, 0.f);
}

__global__ __launch_bounds__(256) void scatter_atomic_kernel(
    const float* __restrict__ feats,
    const int* __restrict__ flat_idx,
    float* __restrict__ out,
    int n_active)
{
    int t = blockIdx.x * blockDim.x + threadIdx.x;
    int i = t >> 5, c = t & 31;
    if (i >= n_active) return;
    int s = flat_idx[i];
    atomicAdd(&out[(((size_t)(s >> DHW_LOG2) * C_CH + c) << DHW_LOG2) + (s & (DHW - 1))],
              feats[(size_t)i * C_CH + c]);
}

extern "C" void kernel_launch(void* const* d_in, const int* in_sizes, int n_in,
                              void* d_out, int out_size, void* d_ws, size_t ws_size,
                              hipStream_t stream) {
    const float* feats = (const float*)d_in[0];
    const int*   idx   = (const int*)d_in[1];
    float*       out   = (float*)d_out;
    int n_active = in_sizes[1];   // 400000

    size_t head_bytes = (size_t)N_SITES_TOTAL * sizeof(int);      // 4 MB
    size_t next_bytes = (size_t)n_active * sizeof(int);           // 1.6 MB

    if (ws_size >= head_bytes + next_bytes) {
        int* head = (int*)d_ws;
        int* next = (int*)((char*)d_ws + head_bytes);

        init_head_kernel<<<(N_SITES_TOTAL + 255) / 256, 256, 0, stream>>>(head, N_SITES_TOTAL);
        build_chains_kernel<<<(n_active + 255) / 256, 256, 0, stream>>>(idx, head, next, n_active);
        // 2 threads per site; 2*2^20 threads = 8192 blocks exactly.
        gather_kernel<<<(2 * N_SITES_TOTAL) / 256, 256, 0, stream>>>(feats, head, next, out);
    } else {
        // fallback: R3 atomic path
        int n4 = out_size >> 2;
        zero_kernel<<<(n4 + 255) / 256, 256, 0, stream>>>((float4*)out, n4);
        int total = n_active * C_CH;
        scatter_atomic_kernel<<<(total + 255) / 256, 256, 0, stream>>>(feats, idx, out, n_active);
    }
}